// Round 2
// baseline (860.971 us; speedup 1.0000x reference)
//
#include <hip/hip_runtime.h>
#include <math.h>

#define B_ 16
#define C_ 64
#define J_ 100        // 1250-sample blocks per (b,c) row
#define T_ 99
#define KW_ 1250      // half-kernel length (K of the GEMM)
#define N_ 192        // 32 oc * 3 kh * 2 halves
#define M_ (B_*C_*J_) // 102400
#define BM 128
#define BK 32
#define NCHUNK 40     // ceil(1250/32) -> zero-padded to 1280

typedef __attribute__((ext_vector_type(8))) _Float16 half8;
typedef __attribute__((ext_vector_type(4))) _Float16 half4_t;
typedef __attribute__((ext_vector_type(4))) float f32x4;
typedef __attribute__((ext_vector_type(4), aligned(4))) float f32x4u; // rows are 1250-strided -> only 8B aligned

// ---------------------------------------------------------------------------
// Kernel 1: GEMM  P[m][n] = sum_k x_block[m][k] * w_half[n][k]
//   m = (b*64 + c)*100 + j   (x viewed as [102400][1250], contiguous)
//   n = o*6 + kh*2 + half    (weights: conv_w[o][kh][half*1250 + k])
// fp16 MFMA 16x16x32 (10 mantissa bits vs bf16's 8 -> 4x less rounding
// error; same MFMA rate), fp32 accumulate. WG tile 128x192, 4 waves 2x2.
// ---------------------------------------------------------------------------
template <typename PT>
__global__ __launch_bounds__(256) void gemm_kernel(const float* __restrict__ x,
                                                   const float* __restrict__ cw,
                                                   PT* __restrict__ P)
{
    __shared__ __align__(16) _Float16 Abf[BM][BK + 8];  // +8 pad keeps 16B align of row starts
    __shared__ __align__(16) _Float16 Bbf[N_][BK + 8];

    const int tid  = threadIdx.x;
    const int bm0  = blockIdx.x * BM;
    const int lane = tid & 63;
    const int wave = tid >> 6;
    const int wm   = (wave & 1) * 64;   // wave's M offset in tile
    const int wn   = (wave >> 1) * 96;  // wave's N offset in tile
    const int l15  = lane & 15;
    const int lq   = lane >> 4;         // 0..3

    // Loop-invariant staging descriptors (A: 128 rows x 8 float4; B: 192 x 8)
    const float* aptr[4]; int adst[4]; int aqc[4];
#pragma unroll
    for (int i = 0; i < 4; i++) {
        int q = i * 256 + tid;
        int r = q >> 3, qc = q & 7;
        aptr[i] = x + (size_t)(bm0 + r) * KW_ + qc * 4;
        adst[i] = r * (BK + 8) + qc * 4;
        aqc[i]  = qc * 4;
    }
    const float* bptr[6]; int bdst[6]; int bqc[6];
#pragma unroll
    for (int i = 0; i < 6; i++) {
        int q = i * 256 + tid;
        int n = q >> 3, qc = q & 7;
        int o = n / 6, rem = n - o * 6, kh = rem >> 1, hf = rem & 1;
        bptr[i] = cw + o * 7500 + kh * 2500 + hf * 1250 + qc * 4;
        bdst[i] = n * (BK + 8) + qc * 4;
        bqc[i]  = qc * 4;
    }

    f32x4 acc[4][6];
#pragma unroll
    for (int mi = 0; mi < 4; mi++)
#pragma unroll
        for (int ni = 0; ni < 6; ni++) acc[mi][ni] = (f32x4){0.f, 0.f, 0.f, 0.f};

    _Float16* As = &Abf[0][0];
    _Float16* Bs = &Bbf[0][0];

    for (int ck = 0; ck < NCHUNK; ck++) {
        const int k0 = ck * BK;
        // ---- stage A (fp32 -> fp16) ----
#pragma unroll
        for (int i = 0; i < 4; i++) {
            float vv[4];
            if (k0 + aqc[i] + 3 < KW_) {
                f32x4u t4 = *(const f32x4u*)(aptr[i] + k0);
                vv[0] = t4.x; vv[1] = t4.y; vv[2] = t4.z; vv[3] = t4.w;
            } else {
#pragma unroll
                for (int u = 0; u < 4; u++) {
                    int k = k0 + aqc[i] + u;
                    vv[u] = (k < KW_) ? aptr[i][k0 + u] : 0.f;
                }
            }
            half4_t s4;
            s4.x = (_Float16)vv[0]; s4.y = (_Float16)vv[1];
            s4.z = (_Float16)vv[2]; s4.w = (_Float16)vv[3];
            *(half4_t*)(As + adst[i]) = s4;
        }
        // ---- stage B (weights, L2-hot) ----
#pragma unroll
        for (int i = 0; i < 6; i++) {
            float vv[4];
            if (k0 + bqc[i] + 3 < KW_) {
                f32x4u t4 = *(const f32x4u*)(bptr[i] + k0);
                vv[0] = t4.x; vv[1] = t4.y; vv[2] = t4.z; vv[3] = t4.w;
            } else {
#pragma unroll
                for (int u = 0; u < 4; u++) {
                    int k = k0 + bqc[i] + u;
                    vv[u] = (k < KW_) ? bptr[i][k0 + u] : 0.f;
                }
            }
            half4_t s4;
            s4.x = (_Float16)vv[0]; s4.y = (_Float16)vv[1];
            s4.z = (_Float16)vv[2]; s4.w = (_Float16)vv[3];
            *(half4_t*)(Bs + bdst[i]) = s4;
        }
        __syncthreads();

        // ---- fragments + MFMA ----
        half8 afr[4], bfr[6];
#pragma unroll
        for (int mi = 0; mi < 4; mi++)
            afr[mi] = *(const half8*)&Abf[wm + mi * 16 + l15][lq * 8];
#pragma unroll
        for (int ni = 0; ni < 6; ni++)
            bfr[ni] = *(const half8*)&Bbf[wn + ni * 16 + l15][lq * 8];
#pragma unroll
        for (int mi = 0; mi < 4; mi++)
#pragma unroll
            for (int ni = 0; ni < 6; ni++)
                acc[mi][ni] = __builtin_amdgcn_mfma_f32_16x16x32_f16(
                    afr[mi], bfr[ni], acc[mi][ni], 0, 0, 0);
        __syncthreads();
    }

    // ---- epilogue: C/D layout col=lane&15, row=(lane>>4)*4+reg ----
#pragma unroll
    for (int mi = 0; mi < 4; mi++) {
        int mrow = bm0 + wm + mi * 16 + lq * 4;
#pragma unroll
        for (int ni = 0; ni < 6; ni++) {
            int n = wn + ni * 16 + l15;
#pragma unroll
            for (int r2 = 0; r2 < 4; r2++)
                P[(size_t)(mrow + r2) * N_ + n] = (PT)acc[mi][ni][r2];
        }
    }
}

// ---------------------------------------------------------------------------
// Kernel 2: combine halves + kh taps (replicate-pad clamp), relu, 1x1 conv,
// relu -> z[b][c][t]. One WG per (t,b); stages P rows for j=t then j=t+1.
// ---------------------------------------------------------------------------
template <typename PT>
__global__ __launch_bounds__(256) void combine_kernel(const PT* __restrict__ P,
                                                      const float* __restrict__ conv_b,
                                                      const float* __restrict__ c2w,
                                                      const float* __restrict__ c2b,
                                                      float* __restrict__ z)
{
    __shared__ float Pl[64][196];   // 196 pad: breaks the 192-stride bank aliasing
    __shared__ float red[4][64];
    const int t   = blockIdx.x;     // 0..98
    const int b   = blockIdx.y;     // 0..15
    const int tid = threadIdx.x;
    const int c   = tid & 63;
    const int og  = tid >> 6;       // 0..3 -> o in [og*8, og*8+8)

    float v[8];
#pragma unroll
    for (int o = 0; o < 8; o++) v[o] = conv_b[og * 8 + o];

    for (int hf = 0; hf < 2; hf++) {
        const int j = t + hf;       // block index, <= 99
        __syncthreads();            // protect Pl from previous phase's readers
        for (int idx = tid; idx < 64 * N_; idx += 256) {
            int r = idx / N_, nn = idx - r * N_;
            Pl[r][nn] = (float)P[((size_t)((b * 64 + r) * J_ + j)) * N_ + nn];
        }
        __syncthreads();
#pragma unroll
        for (int kh = 0; kh < 3; kh++) {
            int r = c + kh - 1;
            r = r < 0 ? 0 : (r > 63 ? 63 : r);   // replicate padding
#pragma unroll
            for (int o = 0; o < 8; o++)
                v[o] += Pl[r][(og * 8 + o) * 6 + kh * 2 + hf];
        }
    }

    float part = 0.f;
#pragma unroll
    for (int o = 0; o < 8; o++) part += fmaxf(v[o], 0.f) * c2w[og * 8 + o];
    red[og][c] = part;
    __syncthreads();
    if (og == 0) {
        float zz = red[0][c] + red[1][c] + red[2][c] + red[3][c] + c2b[0];
        z[(size_t)(b * 64 + c) * T_ + t] = fmaxf(zz, 0.f);
    }
}

// ---------------------------------------------------------------------------
// Kernel 3: scalar Elman RNN over T=99 + sigmoid. One thread per (b,c).
// ---------------------------------------------------------------------------
__global__ __launch_bounds__(256) void rnn_kernel(const float* __restrict__ z,
                                                  const float* __restrict__ w_ih,
                                                  const float* __restrict__ w_hh,
                                                  const float* __restrict__ b_ih,
                                                  const float* __restrict__ b_hh,
                                                  const float* __restrict__ h0,
                                                  float* __restrict__ out)
{
    int g = blockIdx.x * 256 + threadIdx.x;   // 0..1023
    if (g >= B_ * C_) return;
    int b = g >> 6;
    const float wih  = w_ih[0];
    const float whh  = w_hh[0];
    const float bias = b_ih[0] + b_hh[0];
    float h = h0[b];
    const float* zp = z + (size_t)g * T_;
    for (int t = 0; t < T_; t++)
        h = tanhf(fmaf(wih, zp[t], fmaf(whh, h, bias)));
    out[g] = 1.f / (1.f + expf(-h));
}

// ---------------------------------------------------------------------------
extern "C" void kernel_launch(void* const* d_in, const int* in_sizes, int n_in,
                              void* d_out, int out_size, void* d_ws, size_t ws_size,
                              hipStream_t stream)
{
    const float* x   = (const float*)d_in[0];
    const float* cw  = (const float*)d_in[1];
    const float* cb  = (const float*)d_in[2];
    const float* c2w = (const float*)d_in[3];
    const float* c2b = (const float*)d_in[4];
    const float* wih = (const float*)d_in[5];
    const float* whh = (const float*)d_in[6];
    const float* bih = (const float*)d_in[7];
    const float* bhh = (const float*)d_in[8];
    const float* h0  = (const float*)d_in[9];
    float* out = (float*)d_out;

    const size_t pbytes_f32 = (size_t)M_ * N_ * sizeof(float);    // 78.6 MB
    const size_t pbytes_f16 = (size_t)M_ * N_ * sizeof(_Float16); // 39.3 MB
    const size_t zbytes     = (size_t)B_ * C_ * T_ * sizeof(float);

    if (ws_size >= pbytes_f32 + zbytes) {
        float* P = (float*)d_ws;
        float* z = (float*)((char*)d_ws + pbytes_f32);
        gemm_kernel<float><<<M_ / BM, 256, 0, stream>>>(x, cw, P);
        combine_kernel<float><<<dim3(T_, B_), 256, 0, stream>>>(P, cb, c2w, c2b, z);
        rnn_kernel<<<4, 256, 0, stream>>>(z, wih, whh, bih, bhh, h0, out);
    } else if (ws_size >= pbytes_f16 + zbytes) {
        _Float16* P = (_Float16*)d_ws;
        float* z = (float*)((char*)d_ws + pbytes_f16);
        gemm_kernel<_Float16><<<M_ / BM, 256, 0, stream>>>(x, cw, P);
        combine_kernel<_Float16><<<dim3(T_, B_), 256, 0, stream>>>(P, cb, c2w, c2b, z);
        rnn_kernel<<<4, 256, 0, stream>>>(z, wih, whh, bih, bhh, h0, out);
    }
    // else: workspace too small — will fail validation visibly; revisit next round.
}

// Round 4
// 840.414 us; speedup vs baseline: 1.0245x; 1.0245x over previous
//
#include <hip/hip_runtime.h>
#include <math.h>

#define B_ 16
#define C_ 64
#define J_ 100        // 1250-sample blocks per (b,c) row
#define T_ 99
#define KW_ 1250      // half-kernel length (K of the GEMM)
#define KP_ 1280      // K padded to chunk multiple
#define N_ 192        // 32 oc * 3 kh * 2 halves
#define M_ (B_*C_*J_) // 102400
#define BM 128
#define BK 32
#define NCHUNK 40

typedef __attribute__((ext_vector_type(8))) _Float16 half8;
typedef __attribute__((ext_vector_type(4))) float f32x4;
typedef __attribute__((ext_vector_type(2), aligned(8))) float f32x2;  // x rows are 8B-aligned (5000B stride)

#define GLD_LDS16(gp, lp) \
    __builtin_amdgcn_global_load_lds((const __attribute__((address_space(1))) void*)(gp), \
                                     (__attribute__((address_space(3))) void*)(lp), 16, 0, 0)

// ---------------------------------------------------------------------------
// Kernel 0: one-shot weight conversion fp32 -> fp16, padded [192][1280].
// n = o*6 + kh*2 + half; zero tail k>=1250. ~0.5 MB, ~3 us.
// ---------------------------------------------------------------------------
__global__ __launch_bounds__(256) void wconv_kernel(const float* __restrict__ cw,
                                                    _Float16* __restrict__ wh)
{
    int n = blockIdx.x;               // 0..191
    int o = n / 6, rem = n - o * 6, kh = rem >> 1, hf = rem & 1;
    const float* src = cw + o * 7500 + kh * 2500 + hf * 1250;
    for (int k = threadIdx.x; k < KP_; k += 256)
        wh[n * KP_ + k] = (k < KW_) ? (_Float16)src[k] : (_Float16)0.f;
}

// ---------------------------------------------------------------------------
// Kernel 1: GEMM  P[m][n] = sum_k x[m][k] * wh[n][k]
// fp16 MFMA 16x16x32, fp32 acc. WG tile 128x192, 4 waves 2x2 (64x96/wave).
// Double-buffered LDS (one barrier/chunk): B staged via global_load_lds
// width=16 (prefetched 1 chunk ahead into alt buffer), A fp32->fp16 fused
// conversion with distance-2 register prefetch.
// LDS layout [row][32] fp16 unpadded = global_load_lds lane order; frag
// ds_read_b128 pattern is exactly 8 words/bank (balanced, conflict-free).
// R3 bugfix: LOADA double-added the p*8 intra-row offset (ap[] already
// includes it) -> 3/4 of the A tile read shifted k-windows. Load address is
// now ap[u] + k0 + j*2; bounds check keeps the true k.
// ---------------------------------------------------------------------------
__global__ __launch_bounds__(256, 2) void gemm_kernel(const float* __restrict__ x,
                                                      const _Float16* __restrict__ wh,
                                                      float* __restrict__ P)
{
    __shared__ __align__(16) _Float16 sm[2][(BM + N_) * BK];   // 2 x 20 KB

    const int tid  = threadIdx.x;
    const int bm0  = blockIdx.x * BM;
    const int lane = tid & 63;
    const int wave = tid >> 6;
    const int wm   = (wave & 1) * 64;
    const int wn   = (wave >> 1) * 96;
    const int l15  = lane & 15;
    const int lq   = lane >> 4;

    // A staging descriptors: unit u in {0,1}; q=u*256+tid -> row=q>>2, part=q&3
    const float* ap[2]; int koff[2]; int adst[2];
#pragma unroll
    for (int u = 0; u < 2; u++) {
        int q = u * 256 + tid;
        int r = q >> 2, p = q & 3;
        ap[u]   = x + (size_t)(bm0 + r) * KW_ + p * 8;   // p*8 included HERE only
        koff[u] = p * 8;
        adst[u] = q * 8;               // halves
    }
    // B staging descriptors: 3 global_load_lds per wave; qb=(i*4+wave)*64+lane
    const _Float16* bp[3]; int bdst[3];
#pragma unroll
    for (int i = 0; i < 3; i++) {
        int qb = (i * 4 + wave) * 64 + lane;
        int n = qb >> 2, p = qb & 3;
        bp[i]   = wh + n * KP_ + p * 8;
        bdst[i] = (i * 4 + wave) * 512;  // halves; lane*16B appended by HW
    }

    f32x4 acc[4][6];
#pragma unroll
    for (int mi = 0; mi < 4; mi++)
#pragma unroll
        for (int ni = 0; ni < 6; ni++) acc[mi][ni] = (f32x4){0.f, 0.f, 0.f, 0.f};

    f32x2 areg[2][2][4];   // [slot][unit][pair]
#define LOADA(k0, slot)                                                        \
    do {                                                                       \
        _Pragma("unroll") for (int u = 0; u < 2; u++)                          \
        _Pragma("unroll") for (int j = 0; j < 4; j++) {                        \
            int k = (k0) + koff[u] + j * 2;  /* true element index */          \
            areg[slot][u][j] = (k + 2 <= KW_)                                  \
                ? *(const f32x2*)(ap[u] + (k0) + j * 2)                        \
                : (f32x2){0.f, 0.f};                                           \
        }                                                                      \
    } while (0)

    // Prologue: A(0), A(1) into reg slots; B(0) async into buffer 0.
    LOADA(0, 0);
    LOADA(BK, 1);
    {
        _Float16* Bb = &sm[0][BM * BK];
#pragma unroll
        for (int i = 0; i < 3; i++) GLD_LDS16(bp[i], Bb + bdst[i]);
    }

    for (int ck = 0; ck < NCHUNK; ck++) {
        const int slot = ck & 1;
        _Float16* Ab = &sm[slot][0];
        _Float16* Bb = &sm[slot][BM * BK];

        // convert + write A(ck) from regs
#pragma unroll
        for (int u = 0; u < 2; u++) {
            half8 h;
#pragma unroll
            for (int j = 0; j < 4; j++) {
                h[2 * j]     = (_Float16)areg[slot][u][j].x;
                h[2 * j + 1] = (_Float16)areg[slot][u][j].y;
            }
            *(half8*)(Ab + adst[u]) = h;
        }

        __syncthreads();   // publishes A writes; drains B(ck) global_load_lds

        // prefetches into the *other* buffer / freed reg slot (safe: all
        // readers of that buffer finished before this barrier)
        if (ck + 2 < NCHUNK) LOADA((ck + 2) * BK, slot);
        if (ck + 1 < NCHUNK) {
            _Float16* Bn = &sm[slot ^ 1][BM * BK];
            const int k1 = (ck + 1) * BK;
#pragma unroll
            for (int i = 0; i < 3; i++) GLD_LDS16(bp[i] + k1, Bn + bdst[i]);
        }

        // fragments + MFMA
        half8 afr[4], bfr[6];
#pragma unroll
        for (int mi = 0; mi < 4; mi++)
            afr[mi] = *(const half8*)(Ab + (wm + mi * 16 + l15) * BK + lq * 8);
#pragma unroll
        for (int ni = 0; ni < 6; ni++)
            bfr[ni] = *(const half8*)(Bb + (wn + ni * 16 + l15) * BK + lq * 8);
#pragma unroll
        for (int mi = 0; mi < 4; mi++)
#pragma unroll
            for (int ni = 0; ni < 6; ni++)
                acc[mi][ni] = __builtin_amdgcn_mfma_f32_16x16x32_f16(
                    afr[mi], bfr[ni], acc[mi][ni], 0, 0, 0);
        // no trailing barrier: next chunk writes the other buffer
    }

    // epilogue: C/D layout col=lane&15, row=(lane>>4)*4+reg
#pragma unroll
    for (int mi = 0; mi < 4; mi++) {
        int mrow = bm0 + wm + mi * 16 + lq * 4;
#pragma unroll
        for (int ni = 0; ni < 6; ni++) {
            int n = wn + ni * 16 + l15;
#pragma unroll
            for (int r2 = 0; r2 < 4; r2++)
                P[(size_t)(mrow + r2) * N_ + n] = acc[mi][ni][r2];
        }
    }
#undef LOADA
}

// ---------------------------------------------------------------------------
// Kernel 2: combine halves + kh taps (replicate-pad clamp), relu, 1x1 conv,
// relu -> z[b][c][t]. One WG per (t,b).
// ---------------------------------------------------------------------------
__global__ __launch_bounds__(256) void combine_kernel(const float* __restrict__ P,
                                                      const float* __restrict__ conv_b,
                                                      const float* __restrict__ c2w,
                                                      const float* __restrict__ c2b,
                                                      float* __restrict__ z)
{
    __shared__ float Pl[64][196];   // 196 pad: breaks the 192-stride bank aliasing
    __shared__ float red[4][64];
    const int t   = blockIdx.x;     // 0..98
    const int b   = blockIdx.y;     // 0..15
    const int tid = threadIdx.x;
    const int c   = tid & 63;
    const int og  = tid >> 6;       // 0..3 -> o in [og*8, og*8+8)

    float v[8];
#pragma unroll
    for (int o = 0; o < 8; o++) v[o] = conv_b[og * 8 + o];

    for (int hf = 0; hf < 2; hf++) {
        const int j = t + hf;       // block index, <= 99
        __syncthreads();            // protect Pl from previous phase's readers
        for (int idx = tid; idx < 64 * N_; idx += 256) {
            int r = idx / N_, nn = idx - r * N_;
            Pl[r][nn] = P[((size_t)((b * 64 + r) * J_ + j)) * N_ + nn];
        }
        __syncthreads();
#pragma unroll
        for (int kh = 0; kh < 3; kh++) {
            int r = c + kh - 1;
            r = r < 0 ? 0 : (r > 63 ? 63 : r);   // replicate padding
#pragma unroll
            for (int o = 0; o < 8; o++)
                v[o] += Pl[r][(og * 8 + o) * 6 + kh * 2 + hf];
        }
    }

    float part = 0.f;
#pragma unroll
    for (int o = 0; o < 8; o++) part += fmaxf(v[o], 0.f) * c2w[og * 8 + o];
    red[og][c] = part;
    __syncthreads();
    if (og == 0) {
        float zz = red[0][c] + red[1][c] + red[2][c] + red[3][c] + c2b[0];
        z[(size_t)(b * 64 + c) * T_ + t] = fmaxf(zz, 0.f);
    }
}

// ---------------------------------------------------------------------------
// Kernel 3: scalar Elman RNN over T=99 + sigmoid. One thread per (b,c).
// ---------------------------------------------------------------------------
__global__ __launch_bounds__(256) void rnn_kernel(const float* __restrict__ z,
                                                  const float* __restrict__ w_ih,
                                                  const float* __restrict__ w_hh,
                                                  const float* __restrict__ b_ih,
                                                  const float* __restrict__ b_hh,
                                                  const float* __restrict__ h0,
                                                  float* __restrict__ out)
{
    int g = blockIdx.x * 256 + threadIdx.x;   // 0..1023
    if (g >= B_ * C_) return;
    int b = g >> 6;
    const float wih  = w_ih[0];
    const float whh  = w_hh[0];
    const float bias = b_ih[0] + b_hh[0];
    float h = h0[b];
    const float* zp = z + (size_t)g * T_;
    for (int t = 0; t < T_; t++)
        h = tanhf(fmaf(wih, zp[t], fmaf(whh, h, bias)));
    out[g] = 1.f / (1.f + expf(-h));
}

// ---------------------------------------------------------------------------
extern "C" void kernel_launch(void* const* d_in, const int* in_sizes, int n_in,
                              void* d_out, int out_size, void* d_ws, size_t ws_size,
                              hipStream_t stream)
{
    const float* x   = (const float*)d_in[0];
    const float* cw  = (const float*)d_in[1];
    const float* cb  = (const float*)d_in[2];
    const float* c2w = (const float*)d_in[3];
    const float* c2b = (const float*)d_in[4];
    const float* wih = (const float*)d_in[5];
    const float* whh = (const float*)d_in[6];
    const float* bih = (const float*)d_in[7];
    const float* bhh = (const float*)d_in[8];
    const float* h0  = (const float*)d_in[9];
    float* out = (float*)d_out;

    const size_t whbytes = (size_t)N_ * KP_ * sizeof(_Float16);   // 480 KB
    const size_t pbytes  = (size_t)M_ * N_ * sizeof(float);       // 78.6 MB
    const size_t zbytes  = (size_t)B_ * C_ * T_ * sizeof(float);

    if (ws_size < whbytes + pbytes + zbytes) return;  // ws is ~2 GB; never hit

    _Float16* wh = (_Float16*)d_ws;
    float* P = (float*)((char*)d_ws + whbytes);
    float* z = (float*)((char*)d_ws + whbytes + pbytes);

    wconv_kernel<<<N_, 256, 0, stream>>>(cw, wh);
    gemm_kernel<<<M_ / BM, 256, 0, stream>>>(x, wh, P);
    combine_kernel<<<dim3(T_, B_), 256, 0, stream>>>(P, cb, c2w, c2b, z);
    rnn_kernel<<<4, 256, 0, stream>>>(z, wih, whh, bih, bhh, h0, out);
}

// Round 5
// 819.526 us; speedup vs baseline: 1.0506x; 1.0255x over previous
//
#include <hip/hip_runtime.h>
#include <math.h>

#define B_ 16
#define C_ 64
#define J_ 100        // 1250-sample blocks per (b,c) row
#define T_ 99
#define KW_ 1250      // half-kernel length (K of the GEMM)
#define KP_ 1280      // K padded to chunk multiple
#define N_ 192        // 32 oc * 3 kh * 2 halves
#define M_ (B_*C_*J_) // 102400
#define BM 128
#define BK 32
#define NCHUNK 40

typedef __attribute__((ext_vector_type(8))) _Float16 half8;
typedef __attribute__((ext_vector_type(4))) float f32x4;
typedef __attribute__((ext_vector_type(2), aligned(8))) float f32x2;  // x rows are 8B-aligned (5000B stride)

#define GLD_LDS16(gp, lp) \
    __builtin_amdgcn_global_load_lds((const __attribute__((address_space(1))) void*)(gp), \
                                     (__attribute__((address_space(3))) void*)(lp), 16, 0, 0)

// ---------------------------------------------------------------------------
// Kernel 0: one-shot weight conversion fp32 -> fp16, padded [192][1280].
// ---------------------------------------------------------------------------
__global__ __launch_bounds__(256) void wconv_kernel(const float* __restrict__ cw,
                                                    _Float16* __restrict__ wh)
{
    int n = blockIdx.x;               // 0..191
    int o = n / 6, rem = n - o * 6, kh = rem >> 1, hf = rem & 1;
    const float* src = cw + o * 7500 + kh * 2500 + hf * 1250;
    for (int k = threadIdx.x; k < KP_; k += 256)
        wh[n * KP_ + k] = (k < KW_) ? (_Float16)src[k] : (_Float16)0.f;
}

// ---------------------------------------------------------------------------
// Kernel 1: GEMM  P[m'][n] = sum_k x[row(m')][k] * wh[n][k]
//   m' = (b*100 + j)*64 + c   (so each (b,j) block of P is a contiguous
//   64x192 fp16 tile -- what combine consumes in one shot)
//   x row for m' is (b*64+c)*100 + j  (tiles never straddle b: 6400%128==0)
// fp16 MFMA 16x16x32, fp32 acc, P stored fp16. WG tile 128x192, 4 waves 2x2.
// Double-buffered LDS, one barrier/chunk; B via global_load_lds width=16
// (dist-1 prefetch), A fused fp32->fp16 with dist-2 register prefetch.
// ---------------------------------------------------------------------------
__global__ __launch_bounds__(256, 2) void gemm_kernel(const float* __restrict__ x,
                                                      const _Float16* __restrict__ wh,
                                                      _Float16* __restrict__ P)
{
    __shared__ __align__(16) _Float16 sm[2][(BM + N_) * BK];   // 2 x 20 KB

    const int tid  = threadIdx.x;
    const int bm0  = blockIdx.x * BM;
    const int lane = tid & 63;
    const int wave = tid >> 6;
    const int wm   = (wave & 1) * 64;
    const int wn   = (wave >> 1) * 96;
    const int l15  = lane & 15;
    const int lq   = lane >> 4;

    // A staging descriptors: unit u in {0,1}; q=u*256+tid -> row=q>>2, part=q&3
    const float* ap[2]; int koff[2]; int adst[2];
#pragma unroll
    for (int u = 0; u < 2; u++) {
        int q  = u * 256 + tid;
        int rl = q >> 2, p = q & 3;
        int gr = bm0 + rl;                 // m' row
        int b  = gr / 6400;
        int j  = (gr - b * 6400) >> 6;
        int c  = gr & 63;                  // 6400 % 64 == 0
        long xrow = (long)(b * 64 + c) * 100 + j;
        ap[u]   = x + xrow * KW_ + p * 8;  // p*8 included HERE only
        koff[u] = p * 8;
        adst[u] = q * 8;                   // halves
    }
    // B staging descriptors: 3 global_load_lds per wave
    const _Float16* bp[3]; int bdst[3];
#pragma unroll
    for (int i = 0; i < 3; i++) {
        int qb = (i * 4 + wave) * 64 + lane;
        int n = qb >> 2, p = qb & 3;
        bp[i]   = wh + n * KP_ + p * 8;
        bdst[i] = (i * 4 + wave) * 512;  // halves; lane*16B appended by HW
    }

    f32x4 acc[4][6];
#pragma unroll
    for (int mi = 0; mi < 4; mi++)
#pragma unroll
        for (int ni = 0; ni < 6; ni++) acc[mi][ni] = (f32x4){0.f, 0.f, 0.f, 0.f};

    f32x2 areg[2][2][4];   // [slot][unit][pair]
#define LOADA(k0, slot)                                                        \
    do {                                                                       \
        _Pragma("unroll") for (int u = 0; u < 2; u++)                          \
        _Pragma("unroll") for (int j2 = 0; j2 < 4; j2++) {                     \
            int k = (k0) + koff[u] + j2 * 2;  /* true element index */         \
            areg[slot][u][j2] = (k + 2 <= KW_)                                 \
                ? *(const f32x2*)(ap[u] + (k0) + j2 * 2)                       \
                : (f32x2){0.f, 0.f};                                           \
        }                                                                      \
    } while (0)

    // Prologue: A(0), A(1) into reg slots; B(0) async into buffer 0.
    LOADA(0, 0);
    LOADA(BK, 1);
    {
        _Float16* Bb = &sm[0][BM * BK];
#pragma unroll
        for (int i = 0; i < 3; i++) GLD_LDS16(bp[i], Bb + bdst[i]);
    }

    for (int ck = 0; ck < NCHUNK; ck++) {
        const int slot = ck & 1;
        _Float16* Ab = &sm[slot][0];
        _Float16* Bb = &sm[slot][BM * BK];

        // convert + write A(ck) from regs
#pragma unroll
        for (int u = 0; u < 2; u++) {
            half8 h;
#pragma unroll
            for (int j2 = 0; j2 < 4; j2++) {
                h[2 * j2]     = (_Float16)areg[slot][u][j2].x;
                h[2 * j2 + 1] = (_Float16)areg[slot][u][j2].y;
            }
            *(half8*)(Ab + adst[u]) = h;
        }

        __syncthreads();   // publishes A writes; drains B(ck) global_load_lds

        // prefetches into the *other* buffer / freed reg slot
        if (ck + 2 < NCHUNK) LOADA((ck + 2) * BK, slot);
        if (ck + 1 < NCHUNK) {
            _Float16* Bn = &sm[slot ^ 1][BM * BK];
            const int k1 = (ck + 1) * BK;
#pragma unroll
            for (int i = 0; i < 3; i++) GLD_LDS16(bp[i] + k1, Bn + bdst[i]);
        }

        // fragments + MFMA
        half8 afr[4], bfr[6];
#pragma unroll
        for (int mi = 0; mi < 4; mi++)
            afr[mi] = *(const half8*)(Ab + (wm + mi * 16 + l15) * BK + lq * 8);
#pragma unroll
        for (int ni = 0; ni < 6; ni++)
            bfr[ni] = *(const half8*)(Bb + (wn + ni * 16 + l15) * BK + lq * 8);
#pragma unroll
        for (int mi = 0; mi < 4; mi++)
#pragma unroll
            for (int ni = 0; ni < 6; ni++)
                acc[mi][ni] = __builtin_amdgcn_mfma_f32_16x16x32_f16(
                    afr[mi], bfr[ni], acc[mi][ni], 0, 0, 0);
        // no trailing barrier: next chunk writes the other buffer
    }

    // epilogue: C/D layout col=lane&15, row=(lane>>4)*4+reg; store fp16
#pragma unroll
    for (int mi = 0; mi < 4; mi++) {
        int mrow = bm0 + wm + mi * 16 + lq * 4;
#pragma unroll
        for (int ni = 0; ni < 6; ni++) {
            int n = wn + ni * 16 + l15;
#pragma unroll
            for (int r2 = 0; r2 < 4; r2++)
                P[(size_t)(mrow + r2) * N_ + n] = (_Float16)acc[mi][ni][r2];
        }
    }
#undef LOADA
}

// ---------------------------------------------------------------------------
// Kernel 2: combine halves + kh taps (replicate-pad clamp), relu, 1x1 conv,
// relu -> z[t][b*64+c]. One WG per (t,b); P blocks are contiguous fp16.
// LDS pad 193 (=1 mod 32): tap reads stride-193 across r=c -> 2-way = free
// (196 pad was 4 mod 32 -> 8-way conflict, ~2.9x serialization).
// ---------------------------------------------------------------------------
__global__ __launch_bounds__(256) void combine_kernel(const _Float16* __restrict__ P,
                                                      const float* __restrict__ conv_b,
                                                      const float* __restrict__ c2w,
                                                      const float* __restrict__ c2b,
                                                      float* __restrict__ z)
{
    __shared__ float Pl[64][193];
    __shared__ float red[4][64];
    const int t   = blockIdx.x;     // 0..98
    const int b   = blockIdx.y;     // 0..15
    const int tid = threadIdx.x;
    const int c   = tid & 63;
    const int og  = tid >> 6;       // 0..3 -> o in [og*8, og*8+8)

    float v[8];
#pragma unroll
    for (int o = 0; o < 8; o++) v[o] = conv_b[og * 8 + o];

    for (int hf = 0; hf < 2; hf++) {
        const int j = t + hf;       // block index, <= 99
        const _Float16* Pb = P + (size_t)((b * 100 + j) * 64) * N_;  // 64x192 contiguous
        __syncthreads();            // protect Pl from previous phase's readers
#pragma unroll
        for (int i = 0; i < 6; i++) {
            int e   = i * 256 + tid;    // half8 unit index, 0..1535
            half8 h = *(const half8*)(Pb + e * 8);
            int row = e / 24;           // 24 half8 units per 192-wide row
            int col = (e - row * 24) * 8;
#pragma unroll
            for (int u = 0; u < 8; u++) Pl[row][col + u] = (float)h[u];
        }
        __syncthreads();
#pragma unroll
        for (int kh = 0; kh < 3; kh++) {
            int r = c + kh - 1;
            r = r < 0 ? 0 : (r > 63 ? 63 : r);   // replicate padding
#pragma unroll
            for (int o = 0; o < 8; o++)
                v[o] += Pl[r][(og * 8 + o) * 6 + kh * 2 + hf];
        }
    }

    float part = 0.f;
#pragma unroll
    for (int o = 0; o < 8; o++) part += fmaxf(v[o], 0.f) * c2w[og * 8 + o];
    red[og][c] = part;
    __syncthreads();
    if (og == 0) {
        float zz = red[0][c] + red[1][c] + red[2][c] + red[3][c] + c2b[0];
        z[t * (B_ * C_) + b * 64 + c] = fmaxf(zz, 0.f);   // [t][bc] coalesced
    }
}

// ---------------------------------------------------------------------------
// Kernel 3: scalar Elman RNN over T=99 + sigmoid. One thread per (b,c).
// z is [t][bc] -> each timestep read is wave-coalesced.
// ---------------------------------------------------------------------------
__global__ __launch_bounds__(256) void rnn_kernel(const float* __restrict__ z,
                                                  const float* __restrict__ w_ih,
                                                  const float* __restrict__ w_hh,
                                                  const float* __restrict__ b_ih,
                                                  const float* __restrict__ b_hh,
                                                  const float* __restrict__ h0,
                                                  float* __restrict__ out)
{
    int g = blockIdx.x * 256 + threadIdx.x;   // 0..1023 = b*64+c
    if (g >= B_ * C_) return;
    int b = g >> 6;
    const float wih  = w_ih[0];
    const float whh  = w_hh[0];
    const float bias = b_ih[0] + b_hh[0];
    float h = h0[b];
    for (int t = 0; t < T_; t++)
        h = tanhf(fmaf(wih, z[t * (B_ * C_) + g], fmaf(whh, h, bias)));
    out[g] = 1.f / (1.f + expf(-h));
}

// ---------------------------------------------------------------------------
extern "C" void kernel_launch(void* const* d_in, const int* in_sizes, int n_in,
                              void* d_out, int out_size, void* d_ws, size_t ws_size,
                              hipStream_t stream)
{
    const float* x   = (const float*)d_in[0];
    const float* cw  = (const float*)d_in[1];
    const float* cb  = (const float*)d_in[2];
    const float* c2w = (const float*)d_in[3];
    const float* c2b = (const float*)d_in[4];
    const float* wih = (const float*)d_in[5];
    const float* whh = (const float*)d_in[6];
    const float* bih = (const float*)d_in[7];
    const float* bhh = (const float*)d_in[8];
    const float* h0  = (const float*)d_in[9];
    float* out = (float*)d_out;

    const size_t whbytes = (size_t)N_ * KP_ * sizeof(_Float16);   // 480 KB
    const size_t pbytes  = (size_t)M_ * N_ * sizeof(_Float16);    // 39.3 MB
    const size_t zbytes  = (size_t)B_ * C_ * T_ * sizeof(float);

    if (ws_size < whbytes + pbytes + zbytes) return;  // ws is ~2 GB; never hit

    _Float16* wh = (_Float16*)d_ws;
    _Float16* P  = (_Float16*)((char*)d_ws + whbytes);
    float*    z  = (float*)((char*)d_ws + whbytes + pbytes);

    wconv_kernel<<<N_, 256, 0, stream>>>(cw, wh);
    gemm_kernel<<<M_ / BM, 256, 0, stream>>>(x, wh, P);
    combine_kernel<<<dim3(T_, B_), 256, 0, stream>>>(P, cb, c2w, c2b, z);
    rnn_kernel<<<4, 256, 0, stream>>>(z, wih, whh, bih, bhh, h0, out);
}